// Round 1
// 324.574 us; speedup vs baseline: 1.0307x; 1.0307x over previous
//
#include <hip/hip_runtime.h>
#include <math.h>

#define V 100000
#define D 128
#define A 64
#define LVLS 3
#define NN 20000
#define KK 16
#define BK 32
#define ASTRIDE 34   // 32 + 2 pad -> 2-way LDS aliasing only (free)
#define BSTRIDE 68   // 64 + 4 pad
#define PSTRIDE 128  // projAll row: [0,64)=node-half (W1+b), [64,128)=neighbor-half (W2)

// Fused: out = copy(Leaf)  AND  projAll[:,half*64:half*64+64] = Leaf @ W_half (+bias for half 0)
// gridDim.y = 2 selects the half. Register-tiled SGEMM: 128-row tile, 8x4 micro, K chunk 32.
__global__ __launch_bounds__(256, 2)
void projall_kernel(const float* __restrict__ Leaf, const float* __restrict__ Watt,
                    const float* __restrict__ batt, float* __restrict__ projAll,
                    float* __restrict__ outp) {
    __shared__ float As[128 * ASTRIDE];
    __shared__ float Bs[BK * BSTRIDE];
    int t = threadIdx.x;
    int tx = t & 15, ty = t >> 4;
    int r0 = blockIdx.x * 128;
    int half = blockIdx.y;
    const float* Wmat = Watt + (size_t)half * D * A;

    const float* srcp[4];
    int rg[4];
#pragma unroll
    for (int jj = 0; jj < 4; ++jj) {
        int r = r0 + (t >> 3) + 32 * jj;
        rg[jj] = r;
        int rr = r < V ? r : V - 1;
        srcp[jj] = Leaf + (size_t)rr * D + ((t & 7) << 2);
    }

    float4 bv = make_float4(0.f, 0.f, 0.f, 0.f);
    if (half == 0) bv = *(const float4*)(batt + 4 * tx);
    float acc[8][4];
#pragma unroll
    for (int i = 0; i < 8; ++i) {
        acc[i][0] = bv.x; acc[i][1] = bv.y; acc[i][2] = bv.z; acc[i][3] = bv.w;
    }

    for (int k0 = 0; k0 < D; k0 += BK) {
#pragma unroll
        for (int jj = 0; jj < 4; ++jj) {
            float4 v = *(const float4*)(srcp[jj] + k0);
            *(float4*)&As[((t >> 3) + 32 * jj) * ASTRIDE + ((t & 7) << 2)] = v;
            // fused Leaf -> out copy (one half only, guard tail rows)
            if (half == 0 && rg[jj] < V)
                *(float4*)(outp + (size_t)rg[jj] * D + k0 + ((t & 7) << 2)) = v;
        }
#pragma unroll
        for (int ss = 0; ss < 2; ++ss) {
            int s = t + 256 * ss;
            int kB = s >> 4, c4 = (s & 15) << 2;
            *(float4*)&Bs[kB * BSTRIDE + c4] =
                *(const float4*)(Wmat + (size_t)(k0 + kB) * A + c4);
        }
        __syncthreads();
#pragma unroll
        for (int kc = 0; kc < BK; kc += 4) {
            float4 b0 = *(const float4*)&Bs[(kc + 0) * BSTRIDE + 4 * tx];
            float4 b1 = *(const float4*)&Bs[(kc + 1) * BSTRIDE + 4 * tx];
            float4 b2 = *(const float4*)&Bs[(kc + 2) * BSTRIDE + 4 * tx];
            float4 b3 = *(const float4*)&Bs[(kc + 3) * BSTRIDE + 4 * tx];
#pragma unroll
            for (int i = 0; i < 8; ++i) {
                float4 a = *(const float4*)&As[(8 * ty + i) * ASTRIDE + kc];
                acc[i][0] = fmaf(a.x, b0.x, acc[i][0]);
                acc[i][0] = fmaf(a.y, b1.x, acc[i][0]);
                acc[i][0] = fmaf(a.z, b2.x, acc[i][0]);
                acc[i][0] = fmaf(a.w, b3.x, acc[i][0]);
                acc[i][1] = fmaf(a.x, b0.y, acc[i][1]);
                acc[i][1] = fmaf(a.y, b1.y, acc[i][1]);
                acc[i][1] = fmaf(a.z, b2.y, acc[i][1]);
                acc[i][1] = fmaf(a.w, b3.y, acc[i][1]);
                acc[i][2] = fmaf(a.x, b0.z, acc[i][2]);
                acc[i][2] = fmaf(a.y, b1.z, acc[i][2]);
                acc[i][2] = fmaf(a.z, b2.z, acc[i][2]);
                acc[i][2] = fmaf(a.w, b3.z, acc[i][2]);
                acc[i][3] = fmaf(a.x, b0.w, acc[i][3]);
                acc[i][3] = fmaf(a.y, b1.w, acc[i][3]);
                acc[i][3] = fmaf(a.z, b2.w, acc[i][3]);
                acc[i][3] = fmaf(a.w, b3.w, acc[i][3]);
            }
        }
        __syncthreads();
    }

#pragma unroll
    for (int i = 0; i < 8; ++i) {
        int gr = r0 + 8 * ty + i;
        if (gr < V) {
            float4 o = make_float4(acc[i][0], acc[i][1], acc[i][2], acc[i][3]);
            *(float4*)(projAll + (size_t)gr * PSTRIDE + half * 64 + 4 * tx) = o;
        }
    }
}

// Fused scatter (winner rows tmp -> out) + bottom-half proj refresh from the SAME
// contiguously-read tmp rows (no out re-gather). do_proj=0 at the last level.
__global__ __launch_bounds__(256, 2)
void commit_kernel(const float* __restrict__ tmp, const float* __restrict__ Wmat,
                   const int* __restrict__ nodes_l, const int* __restrict__ claim,
                   float* __restrict__ outp, float* __restrict__ projAll, int do_proj) {
    __shared__ float As[128 * ASTRIDE];
    __shared__ float Bs[BK * BSTRIDE];
    int t = threadIdx.x;
    int tx = t & 15, ty = t >> 4;
    int r0 = blockIdx.x * 128;

    const float* srcp[4];
    int vrow[4], win[4];
#pragma unroll
    for (int jj = 0; jj < 4; ++jj) {
        int r = r0 + (t >> 3) + 32 * jj;
        int rr = r < NN ? r : NN - 1;
        srcp[jj] = tmp + (size_t)rr * D + ((t & 7) << 2);
        int v = nodes_l[rr];
        vrow[jj] = v;
        win[jj] = (r < NN) && (claim[v] == rr);  // last-occurrence-wins
    }

    float acc[8][4];
#pragma unroll
    for (int i = 0; i < 8; ++i) {
        acc[i][0] = 0.f; acc[i][1] = 0.f; acc[i][2] = 0.f; acc[i][3] = 0.f;
    }

    for (int k0 = 0; k0 < D; k0 += BK) {
#pragma unroll
        for (int jj = 0; jj < 4; ++jj) {
            float4 v = *(const float4*)(srcp[jj] + k0);
            *(float4*)&As[((t >> 3) + 32 * jj) * ASTRIDE + ((t & 7) << 2)] = v;
            if (win[jj])  // fused scatter into out
                *(float4*)(outp + (size_t)vrow[jj] * D + k0 + ((t & 7) << 2)) = v;
        }
        if (do_proj) {
#pragma unroll
            for (int ss = 0; ss < 2; ++ss) {
                int s = t + 256 * ss;
                int kB = s >> 4, c4 = (s & 15) << 2;
                *(float4*)&Bs[kB * BSTRIDE + c4] =
                    *(const float4*)(Wmat + (size_t)(k0 + kB) * A + c4);
            }
        }
        __syncthreads();
        if (do_proj) {
#pragma unroll
            for (int kc = 0; kc < BK; kc += 4) {
                float4 b0 = *(const float4*)&Bs[(kc + 0) * BSTRIDE + 4 * tx];
                float4 b1 = *(const float4*)&Bs[(kc + 1) * BSTRIDE + 4 * tx];
                float4 b2 = *(const float4*)&Bs[(kc + 2) * BSTRIDE + 4 * tx];
                float4 b3 = *(const float4*)&Bs[(kc + 3) * BSTRIDE + 4 * tx];
#pragma unroll
                for (int i = 0; i < 8; ++i) {
                    float4 a = *(const float4*)&As[(8 * ty + i) * ASTRIDE + kc];
                    acc[i][0] = fmaf(a.x, b0.x, acc[i][0]);
                    acc[i][0] = fmaf(a.y, b1.x, acc[i][0]);
                    acc[i][0] = fmaf(a.z, b2.x, acc[i][0]);
                    acc[i][0] = fmaf(a.w, b3.x, acc[i][0]);
                    acc[i][1] = fmaf(a.x, b0.y, acc[i][1]);
                    acc[i][1] = fmaf(a.y, b1.y, acc[i][1]);
                    acc[i][1] = fmaf(a.z, b2.y, acc[i][1]);
                    acc[i][1] = fmaf(a.w, b3.y, acc[i][1]);
                    acc[i][2] = fmaf(a.x, b0.z, acc[i][2]);
                    acc[i][2] = fmaf(a.y, b1.z, acc[i][2]);
                    acc[i][2] = fmaf(a.z, b2.z, acc[i][2]);
                    acc[i][2] = fmaf(a.w, b3.z, acc[i][2]);
                    acc[i][3] = fmaf(a.x, b0.w, acc[i][3]);
                    acc[i][3] = fmaf(a.y, b1.w, acc[i][3]);
                    acc[i][3] = fmaf(a.z, b2.w, acc[i][3]);
                    acc[i][3] = fmaf(a.w, b3.w, acc[i][3]);
                }
            }
        }
        __syncthreads();
    }

    if (do_proj) {
#pragma unroll
        for (int i = 0; i < 8; ++i) {
            int gr = r0 + 8 * ty + i;
            if (gr < NN) {
                int v = nodes_l[gr];
                if (claim[v] == gr) {
                    float4 o = make_float4(acc[i][0], acc[i][1], acc[i][2], acc[i][3]);
                    *(float4*)(projAll + (size_t)v * PSTRIDE + 64 + 4 * tx) = o;
                }
            }
        }
    }
}

// One wave per node. Reads node-half proj via nodes_l gather (level-invariant,
// Leaf-based) and neighbor-half proj from the refreshed bottom 64 of projAll.
__global__ __launch_bounds__(256)
void attn_kernel(const float* __restrict__ Wc, const float* __restrict__ projAll,
                 const int* __restrict__ nodes_l, const int* __restrict__ neigh,
                 const float* __restrict__ maskp, const float* __restrict__ weightp,
                 const float* __restrict__ v_att, float* __restrict__ tmp) {
    int lane = threadIdx.x & 63;
    int n = blockIdx.x * 4 + (threadIdx.x >> 6);
    int k16 = lane & 15, q = lane >> 4;

    int   vnode = nodes_l[n];
    int   nbk = neigh[n * KK + k16];
    float wv  = weightp[n * KK + k16];
    float mk  = maskp[n * KK + k16];

    const float* npr = projAll + (size_t)vnode * PSTRIDE + q * 16;
    const float* var = v_att + q * 16;
    const float* pr  = projAll + (size_t)nbk * PSTRIDE + 64 + q * 16;

    float part = 0.f;
#pragma unroll
    for (int j = 0; j < 16; j += 4) {
        float4 npv = *(const float4*)(npr + j);
        float4 vav = *(const float4*)(var + j);
        float4 pv  = *(const float4*)(pr + j);
        float x;
        x = npv.x + pv.x; x = fmaxf(x, 0.01f * x); part = fmaf(x, vav.x, part);
        x = npv.y + pv.y; x = fmaxf(x, 0.01f * x); part = fmaf(x, vav.y, part);
        x = npv.z + pv.z; x = fmaxf(x, 0.01f * x); part = fmaf(x, vav.z, part);
        x = npv.w + pv.w; x = fmaxf(x, 0.01f * x); part = fmaf(x, vav.w, part);
    }
    part += __shfl_xor(part, 16);
    part += __shfl_xor(part, 32);
    float pre = part + mk;

    float mp = pre, mw = wv;
#pragma unroll
    for (int off = 8; off >= 1; off >>= 1) {
        mp = fmaxf(mp, __shfl_xor(mp, off));
        mw = fmaxf(mw, __shfl_xor(mw, off));
    }
    float ep = __expf(pre - mp), ew = __expf(wv - mw);
    float sp = ep, sw = ew;
#pragma unroll
    for (int off = 8; off >= 1; off >>= 1) {
        sp += __shfl_xor(sp, off);
        sw += __shfl_xor(sw, off);
    }
    float att = (ep / sp) * (ew / sw);

    // PV: 2 rows/iter, float4/lane, halves summed by one xor-32 at the end.
    int half = lane >> 5, li = lane & 31;
    float ax = 0.f, ay = 0.f, az = 0.f, aw = 0.f;
#pragma unroll
    for (int m = 0; m < 8; ++m) {
        int src = 2 * m + half;
        int nb   = __shfl(nbk, src);
        float ak = __shfl(att, src);
        float4 e = *(const float4*)&Wc[(size_t)nb * D + 4 * li];
        ax = fmaf(e.x, ak, ax); ay = fmaf(e.y, ak, ay);
        az = fmaf(e.z, ak, az); aw = fmaf(e.w, ak, aw);
    }
    ax += __shfl_xor(ax, 32); ay += __shfl_xor(ay, 32);
    az += __shfl_xor(az, 32); aw += __shfl_xor(aw, 32);
    if (half == 0) {
        float4 o = make_float4(ax, ay, az, aw);
        *(float4*)&tmp[(size_t)n * D + 4 * li] = o;
    }
}

// claims for ALL levels in one pass (depends only on nodes input)
__global__ void amax3_kernel(const int* __restrict__ nodes, int* __restrict__ claims, int total) {
    int i = blockIdx.x * 256 + threadIdx.x;
    if (i < total) {
        int lvl = i / NN, pos = i - lvl * NN;
        atomicMax(&claims[(size_t)lvl * V + nodes[i]], pos);
    }
}

extern "C" void kernel_launch(void* const* d_in, const int* in_sizes, int n_in,
                              void* d_out, int out_size, void* d_ws, size_t ws_size,
                              hipStream_t stream) {
    const float* Leaf    = (const float*)d_in[0];
    const int*   nodes   = (const int*)d_in[1];
    const int*   neigh   = (const int*)d_in[2];
    const float* masks   = (const float*)d_in[3];
    const float* weights = (const float*)d_in[4];
    const float* Watt    = (const float*)d_in[5];
    const float* batt    = (const float*)d_in[6];
    const float* vatt    = (const float*)d_in[7];
    float* out = (float*)d_out;

    char* ws = (char*)d_ws;
    float* projAll = (float*)ws;                                    // V*128
    float* tmp     = (float*)(ws + (size_t)V * PSTRIDE * 4);        // NN*D
    int*   claims  = (int*)(ws + (size_t)(V * PSTRIDE + NN * D) * 4); // LVLS*V

    hipMemsetAsync(claims, 0xFF, (size_t)LVLS * V * sizeof(int), stream);  // -1
    amax3_kernel<<<(LVLS * NN + 255) / 256, 256, 0, stream>>>(nodes, claims, LVLS * NN);
    // one pass over Leaf: out copy + both projection halves for all V rows
    projall_kernel<<<dim3((V + 127) / 128, 2), 256, 0, stream>>>(
        Leaf, Watt, batt, projAll, out);

    for (int l = 0; l < LVLS; ++l) {
        const int* nodes_l = nodes + l * NN;
        attn_kernel<<<NN / 4, 256, 0, stream>>>(out, projAll, nodes_l,
                                                neigh + (size_t)l * NN * KK,
                                                masks + (size_t)l * NN * KK,
                                                weights + (size_t)l * NN * KK, vatt, tmp);
        commit_kernel<<<(NN + 127) / 128, 256, 0, stream>>>(
            tmp, Watt + (size_t)D * A, nodes_l, claims + (size_t)l * V, out, projAll,
            (l + 1 < LVLS) ? 1 : 0);
    }
}

// Round 2
// 305.301 us; speedup vs baseline: 1.0957x; 1.0631x over previous
//
#include <hip/hip_runtime.h>
#include <math.h>

#define V 100000
#define D 128
#define A 64
#define LVLS 3
#define NN 20000
#define KK 16
#define BK2 16
#define AST2 18      // 16 + 2 pad
#define BST2 68      // 64 + 4 pad
#define PSTRIDE 128  // projAll row: [0,64)=node-half (W1+b), [64,128)=neighbor-half (W2)

// Fused: out = copy(Leaf)  AND  projAll[:,half*64..] = Leaf @ W_half (+bias half 0).
// gridDim.y = 2 selects the half. 128-row tile, 8x4 micro, BK=16, register-prefetch
// pipeline: loads for chunk c+1 issue BEFORE compute of chunk c; the vmcnt wait
// happens at the next ds_write, i.e. after a full compute phase (latency hidden).
__global__ __launch_bounds__(256, 4)
void projall_kernel(const float* __restrict__ Leaf, const float* __restrict__ Watt,
                    const float* __restrict__ batt, float* __restrict__ projAll,
                    float* __restrict__ outp) {
    __shared__ float As[128 * AST2];  // 9.2 KB
    __shared__ float Bs[BK2 * BST2];  // 4.4 KB
    int t = threadIdx.x;
    int tx = t & 15, ty = t >> 4;
    int r0 = blockIdx.x * 128;
    int half = blockIdx.y;
    const float* Wmat = Watt + (size_t)half * D * A;

    // A staging: 2 rows/thread/chunk, 4 threads cover one row's 16 K-floats
    int ar = t >> 2;            // 0..63
    int ak = (t & 3) << 2;      // 0,4,8,12
    const float* asrc[2];
    int arow[2];
#pragma unroll
    for (int jj = 0; jj < 2; ++jj) {
        int r = r0 + ar + 64 * jj;
        arow[jj] = r;
        int rr = r < V ? r : V - 1;
        asrc[jj] = Leaf + (size_t)rr * D + ak;
    }
    // B staging: 1 float4/thread/chunk
    int bk = t >> 4;            // 0..15 (K within chunk)
    int bc = (t & 15) << 2;     // col*4

    float4 bv = make_float4(0.f, 0.f, 0.f, 0.f);
    if (half == 0) bv = *(const float4*)(batt + 4 * tx);
    float acc[8][4];
#pragma unroll
    for (int i = 0; i < 8; ++i) {
        acc[i][0] = bv.x; acc[i][1] = bv.y; acc[i][2] = bv.z; acc[i][3] = bv.w;
    }

    // prefetch chunk 0
    float4 pa0 = *(const float4*)(asrc[0]);
    float4 pa1 = *(const float4*)(asrc[1]);
    float4 pb  = *(const float4*)(Wmat + (size_t)bk * A + bc);

    for (int k0 = 0; k0 < D; k0 += BK2) {
        if (k0) __syncthreads();          // previous chunk's LDS consumers done
        *(float4*)&As[(ar +  0) * AST2 + ak] = pa0;   // waits vmcnt here (post-compute)
        *(float4*)&As[(ar + 64) * AST2 + ak] = pa1;
        *(float4*)&Bs[bk * BST2 + bc] = pb;
        if (half == 0) {                  // fused Leaf -> out copy
            if (arow[0] < V) *(float4*)(outp + (size_t)arow[0] * D + k0 + ak) = pa0;
            if (arow[1] < V) *(float4*)(outp + (size_t)arow[1] * D + k0 + ak) = pa1;
        }
        __syncthreads();
        int kn = k0 + BK2;
        if (kn < D) {                     // issue next-chunk loads, no wait
            pa0 = *(const float4*)(asrc[0] + kn);
            pa1 = *(const float4*)(asrc[1] + kn);
            pb  = *(const float4*)(Wmat + (size_t)(kn + bk) * A + bc);
        }
#pragma unroll
        for (int kc = 0; kc < BK2; kc += 4) {
            float4 b0 = *(const float4*)&Bs[(kc + 0) * BST2 + 4 * tx];
            float4 b1 = *(const float4*)&Bs[(kc + 1) * BST2 + 4 * tx];
            float4 b2 = *(const float4*)&Bs[(kc + 2) * BST2 + 4 * tx];
            float4 b3 = *(const float4*)&Bs[(kc + 3) * BST2 + 4 * tx];
#pragma unroll
            for (int i = 0; i < 8; ++i) {
                float4 a = *(const float4*)&As[(8 * ty + i) * AST2 + kc];
                acc[i][0] = fmaf(a.x, b0.x, acc[i][0]);
                acc[i][0] = fmaf(a.y, b1.x, acc[i][0]);
                acc[i][0] = fmaf(a.z, b2.x, acc[i][0]);
                acc[i][0] = fmaf(a.w, b3.x, acc[i][0]);
                acc[i][1] = fmaf(a.x, b0.y, acc[i][1]);
                acc[i][1] = fmaf(a.y, b1.y, acc[i][1]);
                acc[i][1] = fmaf(a.z, b2.y, acc[i][1]);
                acc[i][1] = fmaf(a.w, b3.y, acc[i][1]);
                acc[i][2] = fmaf(a.x, b0.z, acc[i][2]);
                acc[i][2] = fmaf(a.y, b1.z, acc[i][2]);
                acc[i][2] = fmaf(a.z, b2.z, acc[i][2]);
                acc[i][2] = fmaf(a.w, b3.z, acc[i][2]);
                acc[i][3] = fmaf(a.x, b0.w, acc[i][3]);
                acc[i][3] = fmaf(a.y, b1.w, acc[i][3]);
                acc[i][3] = fmaf(a.z, b2.w, acc[i][3]);
                acc[i][3] = fmaf(a.w, b3.w, acc[i][3]);
            }
        }
    }

#pragma unroll
    for (int i = 0; i < 8; ++i) {
        int gr = r0 + 8 * ty + i;
        if (gr < V) {
            float4 o = make_float4(acc[i][0], acc[i][1], acc[i][2], acc[i][3]);
            *(float4*)(projAll + (size_t)gr * PSTRIDE + half * 64 + 4 * tx) = o;
        }
    }
}

// Fused scatter (winner rows tmp -> out) + bottom-half proj refresh, same pipeline.
// 64-row tiles (313 blocks vs 157: fills the 256 CUs), micro 4x4, BK=16.
__global__ __launch_bounds__(256, 4)
void commit_kernel(const float* __restrict__ tmp, const float* __restrict__ Wmat,
                   const int* __restrict__ nodes_l, const int* __restrict__ claim,
                   float* __restrict__ outp, float* __restrict__ projAll, int do_proj) {
    __shared__ float As[64 * AST2];   // 4.6 KB
    __shared__ float Bs[BK2 * BST2];  // 4.4 KB
    int t = threadIdx.x;
    int tx = t & 15, ty = t >> 4;     // ty 0..15, 4 rows each
    int r0 = blockIdx.x * 64;

    int ar = t >> 2;                  // 0..63 (one staged row per thread)
    int ak = (t & 3) << 2;
    int r = r0 + ar;
    int rr = r < NN ? r : NN - 1;
    const float* asrc = tmp + (size_t)rr * D + ak;
    int vrow = nodes_l[rr];
    int win = (r < NN) && (claim[vrow] == rr);   // last-occurrence-wins

    int bk = t >> 4;
    int bc = (t & 15) << 2;

    float acc[4][4];
#pragma unroll
    for (int i = 0; i < 4; ++i) {
        acc[i][0] = 0.f; acc[i][1] = 0.f; acc[i][2] = 0.f; acc[i][3] = 0.f;
    }

    float4 pa = *(const float4*)(asrc);
    float4 pb = make_float4(0.f, 0.f, 0.f, 0.f);
    if (do_proj) pb = *(const float4*)(Wmat + (size_t)bk * A + bc);

    for (int k0 = 0; k0 < D; k0 += BK2) {
        if (k0) __syncthreads();
        *(float4*)&As[ar * AST2 + ak] = pa;
        if (do_proj) *(float4*)&Bs[bk * BST2 + bc] = pb;
        if (win)     // fused scatter into out
            *(float4*)(outp + (size_t)vrow * D + k0 + ak) = pa;
        __syncthreads();
        int kn = k0 + BK2;
        if (kn < D) {
            pa = *(const float4*)(asrc + kn);
            if (do_proj) pb = *(const float4*)(Wmat + (size_t)(kn + bk) * A + bc);
        }
        if (do_proj) {
#pragma unroll
            for (int kc = 0; kc < BK2; kc += 4) {
                float4 b0 = *(const float4*)&Bs[(kc + 0) * BST2 + 4 * tx];
                float4 b1 = *(const float4*)&Bs[(kc + 1) * BST2 + 4 * tx];
                float4 b2 = *(const float4*)&Bs[(kc + 2) * BST2 + 4 * tx];
                float4 b3 = *(const float4*)&Bs[(kc + 3) * BST2 + 4 * tx];
#pragma unroll
                for (int i = 0; i < 4; ++i) {
                    float4 a = *(const float4*)&As[(4 * ty + i) * AST2 + kc];
                    acc[i][0] = fmaf(a.x, b0.x, acc[i][0]);
                    acc[i][0] = fmaf(a.y, b1.x, acc[i][0]);
                    acc[i][0] = fmaf(a.z, b2.x, acc[i][0]);
                    acc[i][0] = fmaf(a.w, b3.x, acc[i][0]);
                    acc[i][1] = fmaf(a.x, b0.y, acc[i][1]);
                    acc[i][1] = fmaf(a.y, b1.y, acc[i][1]);
                    acc[i][1] = fmaf(a.z, b2.y, acc[i][1]);
                    acc[i][1] = fmaf(a.w, b3.y, acc[i][1]);
                    acc[i][2] = fmaf(a.x, b0.z, acc[i][2]);
                    acc[i][2] = fmaf(a.y, b1.z, acc[i][2]);
                    acc[i][2] = fmaf(a.z, b2.z, acc[i][2]);
                    acc[i][2] = fmaf(a.w, b3.z, acc[i][2]);
                    acc[i][3] = fmaf(a.x, b0.w, acc[i][3]);
                    acc[i][3] = fmaf(a.y, b1.w, acc[i][3]);
                    acc[i][3] = fmaf(a.z, b2.w, acc[i][3]);
                    acc[i][3] = fmaf(a.w, b3.w, acc[i][3]);
                }
            }
        }
    }

    if (do_proj) {
#pragma unroll
        for (int i = 0; i < 4; ++i) {
            int gr = r0 + 4 * ty + i;
            if (gr < NN) {
                int v = nodes_l[gr];
                if (claim[v] == gr) {
                    float4 o = make_float4(acc[i][0], acc[i][1], acc[i][2], acc[i][3]);
                    *(float4*)(projAll + (size_t)v * PSTRIDE + 64 + 4 * tx) = o;
                }
            }
        }
    }
}

// One wave per node (unchanged math; passed at absmax 0.0039).
__global__ __launch_bounds__(256)
void attn_kernel(const float* __restrict__ Wc, const float* __restrict__ projAll,
                 const int* __restrict__ nodes_l, const int* __restrict__ neigh,
                 const float* __restrict__ maskp, const float* __restrict__ weightp,
                 const float* __restrict__ v_att, float* __restrict__ tmp) {
    int lane = threadIdx.x & 63;
    int n = blockIdx.x * 4 + (threadIdx.x >> 6);
    int k16 = lane & 15, q = lane >> 4;

    int   vnode = nodes_l[n];
    int   nbk = neigh[n * KK + k16];
    float wv  = weightp[n * KK + k16];
    float mk  = maskp[n * KK + k16];

    const float* npr = projAll + (size_t)vnode * PSTRIDE + q * 16;
    const float* var = v_att + q * 16;
    const float* pr  = projAll + (size_t)nbk * PSTRIDE + 64 + q * 16;

    float part = 0.f;
#pragma unroll
    for (int j = 0; j < 16; j += 4) {
        float4 npv = *(const float4*)(npr + j);
        float4 vav = *(const float4*)(var + j);
        float4 pv  = *(const float4*)(pr + j);
        float x;
        x = npv.x + pv.x; x = fmaxf(x, 0.01f * x); part = fmaf(x, vav.x, part);
        x = npv.y + pv.y; x = fmaxf(x, 0.01f * x); part = fmaf(x, vav.y, part);
        x = npv.z + pv.z; x = fmaxf(x, 0.01f * x); part = fmaf(x, vav.z, part);
        x = npv.w + pv.w; x = fmaxf(x, 0.01f * x); part = fmaf(x, vav.w, part);
    }
    part += __shfl_xor(part, 16);
    part += __shfl_xor(part, 32);
    float pre = part + mk;

    float mp = pre, mw = wv;
#pragma unroll
    for (int off = 8; off >= 1; off >>= 1) {
        mp = fmaxf(mp, __shfl_xor(mp, off));
        mw = fmaxf(mw, __shfl_xor(mw, off));
    }
    float ep = __expf(pre - mp), ew = __expf(wv - mw);
    float sp = ep, sw = ew;
#pragma unroll
    for (int off = 8; off >= 1; off >>= 1) {
        sp += __shfl_xor(sp, off);
        sw += __shfl_xor(sw, off);
    }
    float att = (ep / sp) * (ew / sw);

    // PV: 2 rows/iter, float4/lane, halves summed by one xor-32 at the end.
    int half = lane >> 5, li = lane & 31;
    float ax = 0.f, ay = 0.f, az = 0.f, aw = 0.f;
#pragma unroll
    for (int m = 0; m < 8; ++m) {
        int src = 2 * m + half;
        int nb   = __shfl(nbk, src);
        float ak = __shfl(att, src);
        float4 e = *(const float4*)&Wc[(size_t)nb * D + 4 * li];
        ax = fmaf(e.x, ak, ax); ay = fmaf(e.y, ak, ay);
        az = fmaf(e.z, ak, az); aw = fmaf(e.w, ak, aw);
    }
    ax += __shfl_xor(ax, 32); ay += __shfl_xor(ay, 32);
    az += __shfl_xor(az, 32); aw += __shfl_xor(aw, 32);
    if (half == 0) {
        float4 o = make_float4(ax, ay, az, aw);
        *(float4*)&tmp[(size_t)n * D + 4 * li] = o;
    }
}

// claims for ALL levels in one pass (depends only on nodes input)
__global__ void amax3_kernel(const int* __restrict__ nodes, int* __restrict__ claims, int total) {
    int i = blockIdx.x * 256 + threadIdx.x;
    if (i < total) {
        int lvl = i / NN, pos = i - lvl * NN;
        atomicMax(&claims[(size_t)lvl * V + nodes[i]], pos);
    }
}

extern "C" void kernel_launch(void* const* d_in, const int* in_sizes, int n_in,
                              void* d_out, int out_size, void* d_ws, size_t ws_size,
                              hipStream_t stream) {
    const float* Leaf    = (const float*)d_in[0];
    const int*   nodes   = (const int*)d_in[1];
    const int*   neigh   = (const int*)d_in[2];
    const float* masks   = (const float*)d_in[3];
    const float* weights = (const float*)d_in[4];
    const float* Watt    = (const float*)d_in[5];
    const float* batt    = (const float*)d_in[6];
    const float* vatt    = (const float*)d_in[7];
    float* out = (float*)d_out;

    char* ws = (char*)d_ws;
    float* projAll = (float*)ws;                                      // V*128
    float* tmp     = (float*)(ws + (size_t)V * PSTRIDE * 4);          // NN*D
    int*   claims  = (int*)(ws + (size_t)(V * PSTRIDE + NN * D) * 4); // LVLS*V

    hipMemsetAsync(claims, 0xFF, (size_t)LVLS * V * sizeof(int), stream);  // -1
    amax3_kernel<<<(LVLS * NN + 255) / 256, 256, 0, stream>>>(nodes, claims, LVLS * NN);
    // one pass over Leaf: out copy + both projection halves for all V rows
    projall_kernel<<<dim3((V + 127) / 128, 2), 256, 0, stream>>>(
        Leaf, Watt, batt, projAll, out);

    for (int l = 0; l < LVLS; ++l) {
        const int* nodes_l = nodes + l * NN;
        attn_kernel<<<NN / 4, 256, 0, stream>>>(out, projAll, nodes_l,
                                                neigh + (size_t)l * NN * KK,
                                                masks + (size_t)l * NN * KK,
                                                weights + (size_t)l * NN * KK, vatt, tmp);
        commit_kernel<<<(NN + 63) / 64, 256, 0, stream>>>(
            tmp, Watt + (size_t)D * A, nodes_l, claims + (size_t)l * V, out, projAll,
            (l + 1 < LVLS) ? 1 : 0);
    }
}